// Round 1
// baseline (1344.704 us; speedup 1.0000x reference)
//
#include <hip/hip_runtime.h>

typedef __bf16 bf16;
typedef __bf16 bf16x8 __attribute__((ext_vector_type(8)));
typedef float f32x4 __attribute__((ext_vector_type(4)));

#define MFMA16(A,B,C) __builtin_amdgcn_mfma_f32_16x16x32_bf16(A,B,C,0,0,0)
#define SCALE 0.08838834764831843f
#define NEGBIG (-1e30f)

#define AS1(p) ((__attribute__((address_space(1))) void*)(p))
#define AS3(p) ((__attribute__((address_space(3))) void*)(p))

// ---------------- f32 -> bf16 convert ----------------
__global__ void cvt_bf16(const float* __restrict__ src, bf16* __restrict__ dst, int n) {
    int i = (blockIdx.x * 256 + threadIdx.x) * 4;
    if (i < n) {
        float4 v = *(const float4*)(src + i);
        dst[i + 0] = (bf16)v.x; dst[i + 1] = (bf16)v.y;
        dst[i + 2] = (bf16)v.z; dst[i + 3] = (bf16)v.w;
    }
}

// ---------------- LayerNorm + pad to 4096 + bf16 ----------------
__global__ __launch_bounds__(256) void ln_kernel(const float* __restrict__ x,
                                                 const float* __restrict__ w,
                                                 const float* __restrict__ b,
                                                 bf16* __restrict__ xn) {
    int row = blockIdx.x;            // 0..65535  (b*4096 + p)
    int bb = row >> 12, p = row & 4095;
    int t = threadIdx.x;
    bf16* out = xn + ((size_t)row << 10);
    if (p >= 4000) {                 // padded row -> zeros
        uint2 z; z.x = 0u; z.y = 0u;
        *(uint2*)(out + t * 4) = z;
        return;
    }
    float4 v = *(const float4*)(x + (((size_t)bb * 4000 + p) << 10) + t * 4);
    float s = v.x + v.y + v.z + v.w;
    float s2 = v.x * v.x + v.y * v.y + v.z * v.z + v.w * v.w;
#pragma unroll
    for (int m = 1; m < 64; m <<= 1) { s += __shfl_xor(s, m); s2 += __shfl_xor(s2, m); }
    __shared__ float red[8];
    int wv = t >> 6, l = t & 63;
    if (l == 0) { red[wv] = s; red[4 + wv] = s2; }
    __syncthreads();
    s = red[0] + red[1] + red[2] + red[3];
    s2 = red[4] + red[5] + red[6] + red[7];
    float mu = s * (1.f / 1024.f);
    float var = s2 * (1.f / 1024.f) - mu * mu;
    float inv = rsqrtf(var + 1e-5f);
    float4 wv4 = *(const float4*)(w + t * 4);
    float4 bv4 = *(const float4*)(b + t * 4);
    union { bf16 h[4]; uint2 u; } o;
    o.h[0] = (bf16)((v.x - mu) * inv * wv4.x + bv4.x);
    o.h[1] = (bf16)((v.y - mu) * inv * wv4.y + bv4.y);
    o.h[2] = (bf16)((v.z - mu) * inv * wv4.z + bv4.z);
    o.h[3] = (bf16)((v.w - mu) * inv * wv4.w + bv4.w);
    *(uint2*)(out + t * 4) = o.u;
}

// ---------------- bf16 GEMM  C[M][N] = A[M][K] * B[N][K]^T ----------------
// m97 structure: 128x128 tile, BK=32, 4 waves (2x2 of 64x64), global_load_lds w=16.
// EPI=0: bf16 C.  EPI=1: f32 out with row remap (4096-pad -> 4000) + bias.
template <int EPI>
__global__ __launch_bounds__(256, 2) void gemm_bt(const bf16* __restrict__ A,
                                                  const bf16* __restrict__ B,
                                                  bf16* __restrict__ C,
                                                  float* __restrict__ Cf,
                                                  const float* __restrict__ bias,
                                                  int M, int N, int K) {
    __shared__ __align__(16) bf16 As[128 * 32];
    __shared__ __align__(16) bf16 Bs[128 * 32];
    const int tid = threadIdx.x;
    const int w = tid >> 6, l = tid & 63;
    const int lrow = l & 15, lk = l >> 4;
    const int nbk = N >> 7;
    const int m0 = (blockIdx.x / nbk) * 128;
    const int n0 = (blockIdx.x % nbk) * 128;
    const int wr = (w >> 1) * 64, wc = (w & 1) * 64;
    f32x4 acc[4][4] = {};

    for (int k0 = 0; k0 < K; k0 += 32) {
#pragma unroll
        for (int q = 0; q < 2; ++q) {
            int idx = (q * 4 + w) * 64 + l;
            int row = idx >> 2, c8 = idx & 3;
            __builtin_amdgcn_global_load_lds(AS1(A + (size_t)(m0 + row) * K + k0 + c8 * 8),
                                             AS3(&As[(q * 4 + w) * 512]), 16, 0, 0);
            __builtin_amdgcn_global_load_lds(AS1(B + (size_t)(n0 + row) * K + k0 + c8 * 8),
                                             AS3(&Bs[(q * 4 + w) * 512]), 16, 0, 0);
        }
        __syncthreads();
        bf16x8 af[4], bfr[4];
#pragma unroll
        for (int m = 0; m < 4; ++m)
            af[m] = *(const bf16x8*)&As[(wr + m * 16 + lrow) * 32 + lk * 8];
#pragma unroll
        for (int n = 0; n < 4; ++n)
            bfr[n] = *(const bf16x8*)&Bs[(wc + n * 16 + lrow) * 32 + lk * 8];
#pragma unroll
        for (int m = 0; m < 4; ++m)
#pragma unroll
            for (int n = 0; n < 4; ++n)
                acc[m][n] = MFMA16(af[m], bfr[n], acc[m][n]);
        __syncthreads();
    }

    if (EPI == 0) {
#pragma unroll
        for (int m = 0; m < 4; ++m)
#pragma unroll
            for (int r = 0; r < 4; ++r) {
                size_t row = (size_t)(m0 + wr + m * 16 + lk * 4 + r);
#pragma unroll
                for (int n = 0; n < 4; ++n)
                    C[row * N + n0 + wc + n * 16 + lrow] = (bf16)acc[m][n][r];
            }
    } else {
#pragma unroll
        for (int m = 0; m < 4; ++m)
#pragma unroll
            for (int r = 0; r < 4; ++r) {
                int row = m0 + wr + m * 16 + lk * 4 + r;
                int p = row & 4095, bb2 = row >> 12;
                if (p < 4000) {
                    float* dst = Cf + ((size_t)bb2 * 4000 + p) * 1024;
#pragma unroll
                    for (int n = 0; n < 4; ++n) {
                        int col = n0 + wc + n * 16 + lrow;
                        dst[col] = acc[m][n][r] + bias[col];
                    }
                }
            }
    }
}

// ---------------- relative-position bias, skew-materialized ----------------
// blockIdx = bb*8 + g : bb=(b*16+blk)*8+h picks a (batch,block,head); g picks 32 rows.
// W[i][c] = dot(Q[i], rel_emb[257+c]) ; SKEW[bb][i][j] = scale*W[i][i-j+255] (+mask)
__global__ __launch_bounds__(256, 2) void bias_skew(const bf16* __restrict__ qkv,
                                                    const bf16* __restrict__ relw,
                                                    bf16* __restrict__ skew) {
    int bidx = blockIdx.x;
    int g = bidx & 7, bb = bidx >> 3;
    int h = bb & 7, blkn = (bb >> 3) & 15, b = bb >> 7;
    int mrow0 = b * 4096 + blkn * 256 + g * 32;
    const int t = threadIdx.x, w = t >> 6, l = t & 63, lrow = l & 15, lk = l >> 4;
    __shared__ __align__(16) bf16 Qs[32 * 136];
    __shared__ __align__(16) bf16 Ws[32 * 520];

    // stage Q (32 x 128), padded stride 136
#pragma unroll
    for (int q = 0; q < 2; ++q) {
        int idx = q * 256 + t;
        int row = idx >> 4, c8 = idx & 15;
        bf16x8 v = *(const bf16x8*)(qkv + (size_t)(mrow0 + row) * 3072 + h * 128 + c8 * 8);
        *(bf16x8*)&Qs[row * 136 + c8 * 8] = v;
    }
    __syncthreads();

    // W = Q @ relw^T ; wave w owns cols [w*128, w*128+128)
    f32x4 acc[2][8] = {};
#pragma unroll
    for (int ks = 0; ks < 4; ++ks) {
        bf16x8 aq0 = *(const bf16x8*)&Qs[lrow * 136 + ks * 32 + lk * 8];
        bf16x8 aq1 = *(const bf16x8*)&Qs[(16 + lrow) * 136 + ks * 32 + lk * 8];
#pragma unroll
        for (int ct = 0; ct < 8; ++ct) {
            int c = w * 128 + ct * 16 + lrow;
            bf16x8 br = *(const bf16x8*)(relw + (size_t)c * 128 + ks * 32 + lk * 8);
            acc[0][ct] = MFMA16(aq0, br, acc[0][ct]);
            acc[1][ct] = MFMA16(aq1, br, acc[1][ct]);
        }
    }
#pragma unroll
    for (int mt = 0; mt < 2; ++mt)
#pragma unroll
        for (int ct = 0; ct < 8; ++ct)
#pragma unroll
            for (int r = 0; r < 4; ++r)
                Ws[(mt * 16 + lk * 4 + r) * 520 + w * 128 + ct * 16 + lrow] =
                    (bf16)(acc[mt][ct][r] * SCALE);
    __syncthreads();

    // skewed write: SKEW[bb][i][j] = Ws[i_loc][i - j + 255]
    int i_loc = t >> 3, jb = (t & 7) * 32;
    int i_g = g * 32 + i_loc;
    bool last = (blkn == 15);
    const bf16 negbig = (bf16)NEGBIG;
    union { bf16 h[32]; uint4 q4[4]; } ob;
#pragma unroll
    for (int jj = 0; jj < 32; ++jj) {
        int j = jb + jj;
        int c = i_g - j + 255;
        bool masked = last && (i_g >= 160 || j >= 160);
        ob.h[jj] = masked ? negbig : Ws[i_loc * 520 + c];
    }
    uint4* dst = (uint4*)(skew + (size_t)bb * 65536 + (size_t)i_g * 256 + jb);
#pragma unroll
    for (int qq = 0; qq < 4; ++qq) dst[qq] = ob.q4[qq];
}

// ---------------- fused block attention ----------------
// one block per (b,blk,h); 8 waves x 32 query rows; KV tiles of 64, online softmax.
__global__ __launch_bounds__(512, 2) void attn_kernel(const bf16* __restrict__ qkv,
                                                      const bf16* __restrict__ skew,
                                                      bf16* __restrict__ ao) {
    int bb = blockIdx.x;
    int h = bb & 7, blkn = (bb >> 3) & 15, b = bb >> 7;
    const int t = threadIdx.x, w = t >> 6, l = t & 63, lrow = l & 15, lk = l >> 4;
    size_t qrow0 = (size_t)(b * 4096 + blkn * 256);
    __shared__ __align__(16) bf16 Ks[64 * 136];
    __shared__ __align__(16) bf16 Vt[128 * 72];
    __shared__ __align__(16) bf16 Ps[8][32 * 72];

    int i0 = w * 32;
    bf16x8 aq[2][4];
#pragma unroll
    for (int mt = 0; mt < 2; ++mt)
#pragma unroll
        for (int ks = 0; ks < 4; ++ks)
            aq[mt][ks] = *(const bf16x8*)(qkv + (qrow0 + i0 + mt * 16 + lrow) * 3072 +
                                          h * 128 + ks * 32 + lk * 8);

    f32x4 o[2][8] = {};
    float mrun[2][4], lrun[2][4];
#pragma unroll
    for (int mt = 0; mt < 2; ++mt)
#pragma unroll
        for (int r = 0; r < 4; ++r) { mrun[mt][r] = NEGBIG; lrun[mt][r] = 0.f; }

    for (int jt = 0; jt < 4; ++jt) {
        __syncthreads();   // previous iter's LDS reads complete
        // stage K tile (rows jt*64.., padded stride 136)
#pragma unroll
        for (int q = 0; q < 2; ++q) {
            int idx = q * 512 + t;
            int row = idx >> 4, c8 = idx & 15;
            bf16x8 v = *(const bf16x8*)(qkv + (qrow0 + jt * 64 + row) * 3072 + 1024 +
                                        h * 128 + c8 * 8);
            *(bf16x8*)&Ks[row * 136 + c8 * 8] = v;
        }
        // stage V transposed: Vt[d][j]
#pragma unroll
        for (int q = 0; q < 2; ++q) {
            int idx = q * 512 + t;
            int row = idx >> 4, c8 = idx & 15;
            bf16x8 v = *(const bf16x8*)(qkv + (qrow0 + jt * 64 + row) * 3072 + 2048 +
                                        h * 128 + c8 * 8);
#pragma unroll
            for (int e = 0; e < 8; ++e) Vt[(c8 * 8 + e) * 72 + row] = v[e];
        }
        __syncthreads();

        // S = Q K^T (32 x 64 per wave)
        f32x4 s[2][4] = {};
#pragma unroll
        for (int nt = 0; nt < 4; ++nt)
#pragma unroll
            for (int ks = 0; ks < 4; ++ks) {
                bf16x8 bk = *(const bf16x8*)&Ks[(nt * 16 + lrow) * 136 + ks * 32 + lk * 8];
                s[0][nt] = MFMA16(aq[0][ks], bk, s[0][nt]);
                s[1][nt] = MFMA16(aq[1][ks], bk, s[1][nt]);
            }

        // scale + bias
        float sv[2][4][4];
#pragma unroll
        for (int mt = 0; mt < 2; ++mt)
#pragma unroll
            for (int nt = 0; nt < 4; ++nt) {
                size_t sb = (size_t)bb * 65536 + (size_t)(i0 + mt * 16 + lk * 4) * 256 +
                            jt * 64 + nt * 16 + lrow;
#pragma unroll
                for (int r = 0; r < 4; ++r)
                    sv[mt][nt][r] = s[mt][nt][r] * SCALE + (float)skew[sb + (size_t)r * 256];
            }

        // online softmax (row stats across the 16-lane col group)
#pragma unroll
        for (int mt = 0; mt < 2; ++mt)
#pragma unroll
            for (int r = 0; r < 4; ++r) {
                float mx = fmaxf(fmaxf(sv[mt][0][r], sv[mt][1][r]),
                                 fmaxf(sv[mt][2][r], sv[mt][3][r]));
#pragma unroll
                for (int d = 1; d < 16; d <<= 1) mx = fmaxf(mx, __shfl_xor(mx, d));
                float mold = mrun[mt][r];
                float mn = fmaxf(mold, mx);
                float corr = __expf(mold - mn);
                mrun[mt][r] = mn;
                float rs = 0.f;
#pragma unroll
                for (int nt = 0; nt < 4; ++nt) {
                    float e = __expf(sv[mt][nt][r] - mn);
                    sv[mt][nt][r] = e; rs += e;
                }
#pragma unroll
                for (int d = 1; d < 16; d <<= 1) rs += __shfl_xor(rs, d);
                lrun[mt][r] = lrun[mt][r] * corr + rs;
#pragma unroll
                for (int dt = 0; dt < 8; ++dt) o[mt][dt][r] *= corr;
            }

        // P -> per-wave LDS (bf16) to fix A-fragment layout
#pragma unroll
        for (int mt = 0; mt < 2; ++mt)
#pragma unroll
            for (int nt = 0; nt < 4; ++nt)
#pragma unroll
                for (int r = 0; r < 4; ++r)
                    Ps[w][(mt * 16 + lk * 4 + r) * 72 + nt * 16 + lrow] = (bf16)sv[mt][nt][r];

        // O += P @ V
#pragma unroll
        for (int pks = 0; pks < 2; ++pks) {
            bf16x8 ap0 = *(const bf16x8*)&Ps[w][lrow * 72 + pks * 32 + lk * 8];
            bf16x8 ap1 = *(const bf16x8*)&Ps[w][(16 + lrow) * 72 + pks * 32 + lk * 8];
#pragma unroll
            for (int dt = 0; dt < 8; ++dt) {
                bf16x8 bv = *(const bf16x8*)&Vt[(dt * 16 + lrow) * 72 + pks * 32 + lk * 8];
                o[0][dt] = MFMA16(ap0, bv, o[0][dt]);
                o[1][dt] = MFMA16(ap1, bv, o[1][dt]);
            }
        }
    }

    // normalize + store (layout [row][h*128+d] for the output GEMM)
#pragma unroll
    for (int mt = 0; mt < 2; ++mt)
#pragma unroll
        for (int r = 0; r < 4; ++r) {
            float inv = 1.0f / lrun[mt][r];
            size_t arow = qrow0 + i0 + mt * 16 + lk * 4 + r;
            bf16* dst = ao + arow * 1024 + h * 128;
#pragma unroll
            for (int dt = 0; dt < 8; ++dt)
                dst[dt * 16 + lrow] = (bf16)(o[mt][dt][r] * inv);
        }
}

// ---------------- host ----------------
extern "C" void kernel_launch(void* const* d_in, const int* in_sizes, int n_in,
                              void* d_out, int out_size, void* d_ws, size_t ws_size,
                              hipStream_t stream) {
    const float* x   = (const float*)d_in[0];
    const float* lnw = (const float*)d_in[1];
    const float* lnb = (const float*)d_in[2];
    const float* Wq  = (const float*)d_in[3];
    const float* Wkv = (const float*)d_in[4];
    const float* Wo  = (const float*)d_in[5];
    const float* bo  = (const float*)d_in[6];
    const float* rel = (const float*)d_in[7];

    const size_t OFF_XN   = 0;                          // 134,217,728 B (also AO)
    const size_t OFF_QKV  = OFF_XN + 134217728ULL;      // 402,653,184 B
    const size_t OFF_SKEW = OFF_QKV + 402653184ULL;     // 268,435,456 B
    const size_t OFF_WCAT = OFF_SKEW + 268435456ULL;    //   6,291,456 B
    const size_t OFF_WO   = OFF_WCAT + 6291456ULL;      //   2,097,152 B
    const size_t OFF_RELW = OFF_WO + 2097152ULL;        //     131,072 B
    const size_t NEED     = OFF_RELW + 131072ULL;       // ~776 MiB
    if (ws_size < NEED) return;   // diagnostic: will fail validation loudly

    char* ws = (char*)d_ws;
    bf16* xn   = (bf16*)(ws + OFF_XN);
    bf16* qkv  = (bf16*)(ws + OFF_QKV);
    bf16* skw  = (bf16*)(ws + OFF_SKEW);
    bf16* wcat = (bf16*)(ws + OFF_WCAT);
    bf16* wo   = (bf16*)(ws + OFF_WO);
    bf16* relw = (bf16*)(ws + OFF_RELW);
    bf16* ao   = xn;                 // reuse: xn dead after qkv GEMM
    float* out = (float*)d_out;

    cvt_bf16<<<1024, 256, 0, stream>>>(Wq, wcat, 1048576);
    cvt_bf16<<<2048, 256, 0, stream>>>(Wkv, wcat + 1048576, 2097152);
    cvt_bf16<<<1024, 256, 0, stream>>>(Wo, wo, 1048576);
    cvt_bf16<<<64, 256, 0, stream>>>(rel + 257 * 128, relw, 65536);
    ln_kernel<<<65536, 256, 0, stream>>>(x, lnw, lnb, xn);
    gemm_bt<0><<<12288, 256, 0, stream>>>(xn, wcat, qkv, nullptr, nullptr, 65536, 3072, 1024);
    bias_skew<<<16384, 256, 0, stream>>>(qkv, relw, skw);
    attn_kernel<<<2048, 512, 0, stream>>>(qkv, skw, ao);
    gemm_bt<1><<<4096, 256, 0, stream>>>(ao, wo, nullptr, out, bo, 65536, 1024, 1024);
}

// Round 2
// 1273.314 us; speedup vs baseline: 1.0561x; 1.0561x over previous
//
#include <hip/hip_runtime.h>

typedef __bf16 bf16;
typedef __bf16 bf16x8 __attribute__((ext_vector_type(8)));
typedef float f32x4 __attribute__((ext_vector_type(4)));

#define MFMA16(A,B,C) __builtin_amdgcn_mfma_f32_16x16x32_bf16(A,B,C,0,0,0)
#define SCALE 0.08838834764831843f
#define NEGBIG (-1e30f)

#define AS1(p) ((__attribute__((address_space(1))) void*)(p))
#define AS3(p) ((__attribute__((address_space(3))) void*)(p))

#define BAR() do { asm volatile("" ::: "memory"); __builtin_amdgcn_s_barrier(); asm volatile("" ::: "memory"); } while (0)

// ---------------- f32 -> bf16 convert ----------------
__global__ void cvt_bf16(const float* __restrict__ src, bf16* __restrict__ dst, int n) {
    int i = (blockIdx.x * 256 + threadIdx.x) * 4;
    if (i < n) {
        float4 v = *(const float4*)(src + i);
        dst[i + 0] = (bf16)v.x; dst[i + 1] = (bf16)v.y;
        dst[i + 2] = (bf16)v.z; dst[i + 3] = (bf16)v.w;
    }
}

// ---------------- LayerNorm + pad to 4096 + bf16 ----------------
__global__ __launch_bounds__(256) void ln_kernel(const float* __restrict__ x,
                                                 const float* __restrict__ w,
                                                 const float* __restrict__ b,
                                                 bf16* __restrict__ xn) {
    int row = blockIdx.x;            // 0..65535  (b*4096 + p)
    int bb = row >> 12, p = row & 4095;
    int t = threadIdx.x;
    bf16* out = xn + ((size_t)row << 10);
    if (p >= 4000) {                 // padded row -> zeros
        uint2 z; z.x = 0u; z.y = 0u;
        *(uint2*)(out + t * 4) = z;
        return;
    }
    float4 v = *(const float4*)(x + (((size_t)bb * 4000 + p) << 10) + t * 4);
    float s = v.x + v.y + v.z + v.w;
    float s2 = v.x * v.x + v.y * v.y + v.z * v.z + v.w * v.w;
#pragma unroll
    for (int m = 1; m < 64; m <<= 1) { s += __shfl_xor(s, m); s2 += __shfl_xor(s2, m); }
    __shared__ float red[8];
    int wv = t >> 6, l = t & 63;
    if (l == 0) { red[wv] = s; red[4 + wv] = s2; }
    __syncthreads();
    s = red[0] + red[1] + red[2] + red[3];
    s2 = red[4] + red[5] + red[6] + red[7];
    float mu = s * (1.f / 1024.f);
    float var = s2 * (1.f / 1024.f) - mu * mu;
    float inv = rsqrtf(var + 1e-5f);
    float4 wv4 = *(const float4*)(w + t * 4);
    float4 bv4 = *(const float4*)(b + t * 4);
    union { bf16 h[4]; uint2 u; } o;
    o.h[0] = (bf16)((v.x - mu) * inv * wv4.x + bv4.x);
    o.h[1] = (bf16)((v.y - mu) * inv * wv4.y + bv4.y);
    o.h[2] = (bf16)((v.z - mu) * inv * wv4.z + bv4.z);
    o.h[3] = (bf16)((v.w - mu) * inv * wv4.w + bv4.w);
    *(uint2*)(out + t * 4) = o.u;
}

// ================= 256x256 8-phase GEMM (m201 template, plain HIP) =========
// C[M][N] = A[M][K] * B[N][K]^T, bf16 in. 512 thr = 8 waves (2M x 4N),
// BK=64, LDS 128 KiB (2 dbuf x (A 256x64 + B 256x64)), one half-tile staged
// per phase, vmcnt(6) at phases 4/8 only, st_16x32 swizzle via pre-swizzled
// global source (global_load_lds writes linearly) + swizzled ds_read.
// EPI=0: bf16 C.  EPI=1: f32 out with row remap (4096-pad -> 4000) + bias.

__device__ __forceinline__ void stage_half(const bf16* __restrict__ src, int srow, int K,
                                           int kofs, bf16* ldsb, int w, int l) {
#pragma unroll
    for (int r = 0; r < 2; ++r) {
        int rh = (r * 8 + w) * 8 + (l >> 3);          // row within 128-row half
        int chunk = (l & 7) ^ ((rh >> 1) & 2);        // inverse st_16x32 on source
        __builtin_amdgcn_global_load_lds(AS1(src + (size_t)(srow + rh) * K + kofs + chunk * 8),
                                         AS3(ldsb + (r * 8 + w) * 512), 16, 0, 0);
    }
}

__device__ __forceinline__ bf16x8 fragLD(const bf16* base, int row, int ks, int lk) {
    // swizzled read: col ^= 16 elements when row bit2 set (byte-bit5 ^= byte-bit9)
    return *(const bf16x8*)(base + row * 64 + ((ks * 32 + lk * 8) ^ ((row & 4) << 2)));
}

#define RDA(AF, base, mofs) \
    _Pragma("unroll") for (int m = 0; m < 4; ++m) \
    _Pragma("unroll") for (int ks = 0; ks < 2; ++ks) \
        AF[m][ks] = fragLD(base, rA + (mofs + m) * 16 + lrow, ks, lk);

#define RDB2(nb, base) \
    _Pragma("unroll") for (int n = 0; n < 2; ++n) \
    _Pragma("unroll") for (int ks = 0; ks < 2; ++ks) \
        bfr[(nb) + n][ks] = fragLD(base, rB + ((nb) + n) * 16 + lrow, ks, lk);

#define MM(mb, AF, nb) do { \
    __builtin_amdgcn_s_setprio(1); \
    _Pragma("unroll") for (int m = 0; m < 4; ++m) \
    _Pragma("unroll") for (int n = 0; n < 2; ++n) \
    _Pragma("unroll") for (int ks = 0; ks < 2; ++ks) \
        acc[(mb) + m][(nb) + n] = MFMA16(AF[m][ks], bfr[(nb) + n][ks], acc[(mb) + m][(nb) + n]); \
    __builtin_amdgcn_s_setprio(0); } while (0)

template <int EPI>
__global__ __launch_bounds__(512, 2) void gemm256(const bf16* __restrict__ A,
                                                  const bf16* __restrict__ B,
                                                  bf16* __restrict__ C,
                                                  float* __restrict__ Cf,
                                                  const float* __restrict__ bias,
                                                  int M, int N, int K) {
    __shared__ __align__(16) bf16 LA[2 * 16384];
    __shared__ __align__(16) bf16 LB[2 * 16384];
    const int t = threadIdx.x;
    const int w = t >> 6, l = t & 63;
    const int lrow = l & 15, lk = l >> 4;
    const int wrM = w >> 2, wn = w & 3;
    const int rA = wrM * 128, rB = wn * 64;

    // bijective XCD swizzle (grids here are divisible by 8)
    const int nwg = gridDim.x, cpx = nwg >> 3;
    const int swz = ((int)blockIdx.x & 7) * cpx + ((int)blockIdx.x >> 3);
    const int nbk = N >> 8;
    const int m0 = (swz / nbk) * 256;
    const int n0 = (swz % nbk) * 256;

    bf16* LA0 = LA;          bf16* LB0 = LB;          // even K-tiles
    bf16* LA1 = LA + 16384;  bf16* LB1 = LB + 16384;  // odd K-tiles

    f32x4 acc[8][4] = {};
    bf16x8 afL[4][2], afH[4][2], bfr[4][2];

    const int NT = K >> 6, NI = K >> 7;

    // ---- prologue: tile0 fully + tile1 {B-lo,B-hi,A-lo}; drain tile0 ----
    stage_half(B, n0,       K, 0,  LB0,        w, l);
    stage_half(B, n0 + 128, K, 0,  LB0 + 8192, w, l);
    stage_half(A, m0,       K, 0,  LA0,        w, l);
    stage_half(A, m0 + 128, K, 0,  LA0 + 8192, w, l);
    stage_half(B, n0,       K, 64, LB1,        w, l);
    stage_half(B, n0 + 128, K, 64, LB1 + 8192, w, l);
    stage_half(A, m0,       K, 64, LA1,        w, l);
    asm volatile("s_waitcnt vmcnt(6)" ::: "memory");
    BAR();

    for (int i = 0; i < NI; ++i) {
        const int kS1 = (2 * i + 1) << 6;
        const int t2 = 2 * i + 2, t3 = 2 * i + 3;
        const int kS2 = ((t2 < NT) ? t2 : NT - 1) << 6;
        const int kS3 = ((t3 < NT) ? t3 : NT - 1) << 6;

        // ---- P1: Q1 of even tile ----
        RDA(afL, LA0, 0);
        if (wn < 2) { RDB2(0, LB0); RDB2(2, LB0); } else { RDB2(0, LB0); }
        stage_half(A, m0 + 128, K, kS1, LA1 + 8192, w, l);   // odd tile A-hi
        BAR();
        MM(0, afL, 0);
        BAR();
        // ---- P2: Q2 ----
        if (wn >= 2) { RDB2(2, LB0); }
        stage_half(B, n0, K, kS2, LB0, w, l);                // t+2 B-lo
        BAR();
        MM(0, afL, 2);
        BAR();
        // ---- P3: Q3 ----
        RDA(afH, LA0, 4);
        stage_half(B, n0 + 128, K, kS2, LB0 + 8192, w, l);   // t+2 B-hi
        BAR();
        MM(4, afH, 0);
        BAR();
        // ---- P4: Q4 + counted drain ----
        stage_half(A, m0, K, kS2, LA0, w, l);                // t+2 A-lo
        BAR();
        MM(4, afH, 2);
        asm volatile("s_waitcnt vmcnt(6)" ::: "memory");
        BAR();
        // ---- P5: Q1 of odd tile ----
        RDA(afL, LA1, 0);
        if (wn < 2) { RDB2(0, LB1); RDB2(2, LB1); } else { RDB2(0, LB1); }
        stage_half(A, m0 + 128, K, kS2, LA0 + 8192, w, l);   // t+2 A-hi
        BAR();
        MM(0, afL, 0);
        BAR();
        // ---- P6: Q2 ----
        if (wn >= 2) { RDB2(2, LB1); }
        stage_half(B, n0, K, kS3, LB1, w, l);                // t+3 B-lo
        BAR();
        MM(0, afL, 2);
        BAR();
        // ---- P7: Q3 ----
        RDA(afH, LA1, 4);
        stage_half(B, n0 + 128, K, kS3, LB1 + 8192, w, l);   // t+3 B-hi
        BAR();
        MM(4, afH, 0);
        BAR();
        // ---- P8: Q4 + counted drain ----
        stage_half(A, m0, K, kS3, LA1, w, l);                // t+3 A-lo
        BAR();
        MM(4, afH, 2);
        asm volatile("s_waitcnt vmcnt(6)" ::: "memory");
        BAR();
    }

    asm volatile("s_waitcnt vmcnt(0)" ::: "memory");

    if (EPI == 0) {
#pragma unroll
        for (int m = 0; m < 8; ++m)
#pragma unroll
            for (int r = 0; r < 4; ++r) {
                size_t row = (size_t)(m0 + rA + m * 16 + lk * 4 + r);
                bf16* dst = C + row * N + n0 + rB;
#pragma unroll
                for (int n = 0; n < 4; ++n) dst[n * 16 + lrow] = (bf16)acc[m][n][r];
            }
    } else {
#pragma unroll
        for (int m = 0; m < 8; ++m)
#pragma unroll
            for (int r = 0; r < 4; ++r) {
                int row = m0 + rA + m * 16 + lk * 4 + r;
                int p = row & 4095, bb2 = row >> 12;
                if (p < 4000) {
                    float* dst = Cf + ((size_t)bb2 * 4000 + p) * 1024 + n0 + rB;
#pragma unroll
                    for (int n = 0; n < 4; ++n)
                        dst[n * 16 + lrow] = acc[m][n][r] + bias[n0 + rB + n * 16 + lrow];
                }
            }
    }
}

// ---------------- relative-position bias, skew-materialized ----------------
// blockIdx = bb*8 + g : bb=(b*16+blk)*8+h ; g picks 32 rows.
// W[i][c] = dot(Q[i], rel_emb[257+c]) ; logical SKEW[i][j] = scale*W[i][i-j+255]
// Stored PERMUTED for attn's MFMA C-layout: skewP[((bb*8+g)*4+jt)*64+l][e],
// e = mt*16+nt*4+r  ->  lane l of attn wave g reads 32 contiguous bf16.
__global__ __launch_bounds__(256, 2) void bias_skew(const bf16* __restrict__ qkv,
                                                    const bf16* __restrict__ relw,
                                                    bf16* __restrict__ skew) {
    int bidx = blockIdx.x;
    int g = bidx & 7, bb = bidx >> 3;
    int h = bb & 7, blkn = (bb >> 3) & 15, b = bb >> 7;
    int mrow0 = b * 4096 + blkn * 256 + g * 32;
    const int t = threadIdx.x, w = t >> 6, l = t & 63, lrow = l & 15, lk = l >> 4;
    __shared__ __align__(16) bf16 Qs[32 * 136];
    __shared__ __align__(16) bf16 Ws[32 * 520];

    // stage Q (32 x 128), padded stride 136
#pragma unroll
    for (int q = 0; q < 2; ++q) {
        int idx = q * 256 + t;
        int row = idx >> 4, c8 = idx & 15;
        bf16x8 v = *(const bf16x8*)(qkv + (size_t)(mrow0 + row) * 3072 + h * 128 + c8 * 8);
        *(bf16x8*)&Qs[row * 136 + c8 * 8] = v;
    }
    __syncthreads();

    // W = Q @ relw^T ; wave w owns cols [w*128, w*128+128)
    f32x4 acc[2][8] = {};
#pragma unroll
    for (int ks = 0; ks < 4; ++ks) {
        bf16x8 aq0 = *(const bf16x8*)&Qs[lrow * 136 + ks * 32 + lk * 8];
        bf16x8 aq1 = *(const bf16x8*)&Qs[(16 + lrow) * 136 + ks * 32 + lk * 8];
#pragma unroll
        for (int ct = 0; ct < 8; ++ct) {
            int c = w * 128 + ct * 16 + lrow;
            bf16x8 br = *(const bf16x8*)(relw + (size_t)c * 128 + ks * 32 + lk * 8);
            acc[0][ct] = MFMA16(aq0, br, acc[0][ct]);
            acc[1][ct] = MFMA16(aq1, br, acc[1][ct]);
        }
    }
#pragma unroll
    for (int mt = 0; mt < 2; ++mt)
#pragma unroll
        for (int ct = 0; ct < 8; ++ct)
#pragma unroll
            for (int r = 0; r < 4; ++r)
                Ws[(mt * 16 + lk * 4 + r) * 520 + w * 128 + ct * 16 + lrow] =
                    (bf16)(acc[mt][ct][r] * SCALE);
    __syncthreads();

    // permuted skew write
    int jt = t >> 6, ll = t & 63;
    bool last = (blkn == 15);
    const bf16 negbig = (bf16)NEGBIG;
    union { bf16 hh[32]; uint4 q4[4]; } ob;
#pragma unroll
    for (int e = 0; e < 32; ++e) {
        int mt = e >> 4, nt = (e >> 2) & 3, r = e & 3;
        int iloc = mt * 16 + (ll >> 4) * 4 + r;
        int j = jt * 64 + nt * 16 + (ll & 15);
        int ig = g * 32 + iloc;
        int c = ig - j + 255;
        bool masked = last && (ig >= 160 || j >= 160);
        ob.hh[e] = masked ? negbig : Ws[iloc * 520 + c];
    }
    uint4* dst = (uint4*)(skew + ((((size_t)bb * 8 + g) * 4 + jt) * 64 + ll) * 32);
#pragma unroll
    for (int qq = 0; qq < 4; ++qq) dst[qq] = ob.q4[qq];
}

// ---------------- fused block attention ----------------
// one block per (b,blk,h); 8 waves x 32 query rows; KV tiles of 64, online softmax.
__global__ __launch_bounds__(512, 2) void attn_kernel(const bf16* __restrict__ qkv,
                                                      const bf16* __restrict__ skew,
                                                      bf16* __restrict__ ao) {
    int bb = blockIdx.x;
    int h = bb & 7, blkn = (bb >> 3) & 15, b = bb >> 7;
    const int t = threadIdx.x, w = t >> 6, l = t & 63, lrow = l & 15, lk = l >> 4;
    size_t qrow0 = (size_t)(b * 4096 + blkn * 256);
    __shared__ __align__(16) bf16 Ks[64 * 136];
    __shared__ __align__(16) bf16 Vt[128 * 72];
    __shared__ __align__(16) bf16 Ps[8][32 * 72];

    int i0 = w * 32;
    bf16x8 aq[2][4];
#pragma unroll
    for (int mt = 0; mt < 2; ++mt)
#pragma unroll
        for (int ks = 0; ks < 4; ++ks)
            aq[mt][ks] = *(const bf16x8*)(qkv + (qrow0 + i0 + mt * 16 + lrow) * 3072 +
                                          h * 128 + ks * 32 + lk * 8);

    f32x4 o[2][8] = {};
    float mrun[2][4], lrun[2][4];
#pragma unroll
    for (int mt = 0; mt < 2; ++mt)
#pragma unroll
        for (int r = 0; r < 4; ++r) { mrun[mt][r] = NEGBIG; lrun[mt][r] = 0.f; }

    for (int jt = 0; jt < 4; ++jt) {
        __syncthreads();   // previous iter's LDS reads complete
        // stage K tile (rows jt*64.., padded stride 136)
#pragma unroll
        for (int q = 0; q < 2; ++q) {
            int idx = q * 512 + t;
            int row = idx >> 4, c8 = idx & 15;
            bf16x8 v = *(const bf16x8*)(qkv + (qrow0 + jt * 64 + row) * 3072 + 1024 +
                                        h * 128 + c8 * 8);
            *(bf16x8*)&Ks[row * 136 + c8 * 8] = v;
        }
        // stage V transposed: Vt[d][j]
#pragma unroll
        for (int q = 0; q < 2; ++q) {
            int idx = q * 512 + t;
            int row = idx >> 4, c8 = idx & 15;
            bf16x8 v = *(const bf16x8*)(qkv + (qrow0 + jt * 64 + row) * 3072 + 2048 +
                                        h * 128 + c8 * 8);
#pragma unroll
            for (int e = 0; e < 8; ++e) Vt[(c8 * 8 + e) * 72 + row] = v[e];
        }
        __syncthreads();

        // S = Q K^T (32 x 64 per wave)
        f32x4 s[2][4] = {};
#pragma unroll
        for (int nt = 0; nt < 4; ++nt)
#pragma unroll
            for (int ks = 0; ks < 4; ++ks) {
                bf16x8 bk = *(const bf16x8*)&Ks[(nt * 16 + lrow) * 136 + ks * 32 + lk * 8];
                s[0][nt] = MFMA16(aq[0][ks], bk, s[0][nt]);
                s[1][nt] = MFMA16(aq[1][ks], bk, s[1][nt]);
            }

        // scale + bias (permuted skew: 4 x 16B contiguous loads per lane)
        bf16x8 sk[4];
        const bf16x8* sp = (const bf16x8*)(skew +
                            ((((size_t)bb * 8 + w) * 4 + jt) * 64 + l) * 32);
        sk[0] = sp[0]; sk[1] = sp[1]; sk[2] = sp[2]; sk[3] = sp[3];
        float sv[2][4][4];
#pragma unroll
        for (int mt = 0; mt < 2; ++mt)
#pragma unroll
            for (int nt = 0; nt < 4; ++nt)
#pragma unroll
                for (int r = 0; r < 4; ++r)
                    sv[mt][nt][r] = s[mt][nt][r] * SCALE +
                                    (float)sk[mt * 2 + (nt >> 1)][(nt & 1) * 4 + r];

        // online softmax (row stats across the 16-lane col group)
#pragma unroll
        for (int mt = 0; mt < 2; ++mt)
#pragma unroll
            for (int r = 0; r < 4; ++r) {
                float mx = fmaxf(fmaxf(sv[mt][0][r], sv[mt][1][r]),
                                 fmaxf(sv[mt][2][r], sv[mt][3][r]));
#pragma unroll
                for (int d = 1; d < 16; d <<= 1) mx = fmaxf(mx, __shfl_xor(mx, d));
                float mold = mrun[mt][r];
                float mn = fmaxf(mold, mx);
                float corr = __expf(mold - mn);
                mrun[mt][r] = mn;
                float rs = 0.f;
#pragma unroll
                for (int nt = 0; nt < 4; ++nt) {
                    float e = __expf(sv[mt][nt][r] - mn);
                    sv[mt][nt][r] = e; rs += e;
                }
#pragma unroll
                for (int d = 1; d < 16; d <<= 1) rs += __shfl_xor(rs, d);
                lrun[mt][r] = lrun[mt][r] * corr + rs;
#pragma unroll
                for (int dt = 0; dt < 8; ++dt) o[mt][dt][r] *= corr;
            }

        // P -> per-wave LDS (bf16) to fix A-fragment layout
#pragma unroll
        for (int mt = 0; mt < 2; ++mt)
#pragma unroll
            for (int nt = 0; nt < 4; ++nt)
#pragma unroll
                for (int r = 0; r < 4; ++r)
                    Ps[w][(mt * 16 + lk * 4 + r) * 72 + nt * 16 + lrow] = (bf16)sv[mt][nt][r];

        // O += P @ V
#pragma unroll
        for (int pks = 0; pks < 2; ++pks) {
            bf16x8 ap0 = *(const bf16x8*)&Ps[w][lrow * 72 + pks * 32 + lk * 8];
            bf16x8 ap1 = *(const bf16x8*)&Ps[w][(16 + lrow) * 72 + pks * 32 + lk * 8];
#pragma unroll
            for (int dt = 0; dt < 8; ++dt) {
                bf16x8 bv = *(const bf16x8*)&Vt[(dt * 16 + lrow) * 72 + pks * 32 + lk * 8];
                o[0][dt] = MFMA16(ap0, bv, o[0][dt]);
                o[1][dt] = MFMA16(ap1, bv, o[1][dt]);
            }
        }
    }

    // normalize + store (layout [row][h*128+d] for the output GEMM)
#pragma unroll
    for (int mt = 0; mt < 2; ++mt)
#pragma unroll
        for (int r = 0; r < 4; ++r) {
            float inv = 1.0f / lrun[mt][r];
            size_t arow = qrow0 + i0 + mt * 16 + lk * 4 + r;
            bf16* dst = ao + arow * 1024 + h * 128;
#pragma unroll
            for (int dt = 0; dt < 8; ++dt)
                dst[dt * 16 + lrow] = (bf16)(o[mt][dt][r] * inv);
        }
}

// ---------------- host ----------------
extern "C" void kernel_launch(void* const* d_in, const int* in_sizes, int n_in,
                              void* d_out, int out_size, void* d_ws, size_t ws_size,
                              hipStream_t stream) {
    const float* x   = (const float*)d_in[0];
    const float* lnw = (const float*)d_in[1];
    const float* lnb = (const float*)d_in[2];
    const float* Wq  = (const float*)d_in[3];
    const float* Wkv = (const float*)d_in[4];
    const float* Wo  = (const float*)d_in[5];
    const float* bo  = (const float*)d_in[6];
    const float* rel = (const float*)d_in[7];

    const size_t OFF_XN   = 0;                          // 134,217,728 B (also AO)
    const size_t OFF_QKV  = OFF_XN + 134217728ULL;      // 402,653,184 B
    const size_t OFF_SKEW = OFF_QKV + 402653184ULL;     // 268,435,456 B
    const size_t OFF_WCAT = OFF_SKEW + 268435456ULL;    //   6,291,456 B
    const size_t OFF_WO   = OFF_WCAT + 6291456ULL;      //   2,097,152 B
    const size_t OFF_RELW = OFF_WO + 2097152ULL;        //     131,072 B
    const size_t NEED     = OFF_RELW + 131072ULL;       // ~776 MiB
    if (ws_size < NEED) return;   // diagnostic: will fail validation loudly

    char* ws = (char*)d_ws;
    bf16* xn   = (bf16*)(ws + OFF_XN);
    bf16* qkv  = (bf16*)(ws + OFF_QKV);
    bf16* skw  = (bf16*)(ws + OFF_SKEW);
    bf16* wcat = (bf16*)(ws + OFF_WCAT);
    bf16* wo   = (bf16*)(ws + OFF_WO);
    bf16* relw = (bf16*)(ws + OFF_RELW);
    bf16* ao   = xn;                 // reuse: xn dead after qkv GEMM
    float* out = (float*)d_out;

    cvt_bf16<<<1024, 256, 0, stream>>>(Wq, wcat, 1048576);
    cvt_bf16<<<2048, 256, 0, stream>>>(Wkv, wcat + 1048576, 2097152);
    cvt_bf16<<<1024, 256, 0, stream>>>(Wo, wo, 1048576);
    cvt_bf16<<<64, 256, 0, stream>>>(rel + 257 * 128, relw, 65536);
    ln_kernel<<<65536, 256, 0, stream>>>(x, lnw, lnb, xn);
    gemm256<0><<<3072, 512, 0, stream>>>(xn, wcat, qkv, nullptr, nullptr, 65536, 3072, 1024);
    bias_skew<<<16384, 256, 0, stream>>>(qkv, relw, skw);
    attn_kernel<<<2048, 512, 0, stream>>>(qkv, skw, ao);
    gemm256<1><<<1024, 512, 0, stream>>>(ao, wo, nullptr, out, bo, 65536, 1024, 1024);
}

// Round 3
// 1228.266 us; speedup vs baseline: 1.0948x; 1.0367x over previous
//
#include <hip/hip_runtime.h>

typedef __bf16 bf16;
typedef __bf16 bf16x8 __attribute__((ext_vector_type(8)));
typedef float f32x4 __attribute__((ext_vector_type(4)));

#define MFMA16(A,B,C) __builtin_amdgcn_mfma_f32_16x16x32_bf16(A,B,C,0,0,0)
#define SCALE 0.08838834764831843f
#define NEGBIG (-1e30f)

#define AS1(p) ((__attribute__((address_space(1))) void*)(p))
#define AS3(p) ((__attribute__((address_space(3))) void*)(p))

#define BAR() do { asm volatile("" ::: "memory"); __builtin_amdgcn_s_barrier(); asm volatile("" ::: "memory"); } while (0)

// ---------------- f32 -> bf16 convert ----------------
__global__ void cvt_bf16(const float* __restrict__ src, bf16* __restrict__ dst, int n) {
    int i = (blockIdx.x * 256 + threadIdx.x) * 4;
    if (i < n) {
        float4 v = *(const float4*)(src + i);
        dst[i + 0] = (bf16)v.x; dst[i + 1] = (bf16)v.y;
        dst[i + 2] = (bf16)v.z; dst[i + 3] = (bf16)v.w;
    }
}

// ---------------- LayerNorm + pad to 4096 + bf16 ----------------
__global__ __launch_bounds__(256) void ln_kernel(const float* __restrict__ x,
                                                 const float* __restrict__ w,
                                                 const float* __restrict__ b,
                                                 bf16* __restrict__ xn) {
    int row = blockIdx.x;            // 0..65535  (b*4096 + p)
    int bb = row >> 12, p = row & 4095;
    int t = threadIdx.x;
    bf16* out = xn + ((size_t)row << 10);
    if (p >= 4000) {                 // padded row -> zeros
        uint2 z; z.x = 0u; z.y = 0u;
        *(uint2*)(out + t * 4) = z;
        return;
    }
    float4 v = *(const float4*)(x + (((size_t)bb * 4000 + p) << 10) + t * 4);
    float s = v.x + v.y + v.z + v.w;
    float s2 = v.x * v.x + v.y * v.y + v.z * v.z + v.w * v.w;
#pragma unroll
    for (int m = 1; m < 64; m <<= 1) { s += __shfl_xor(s, m); s2 += __shfl_xor(s2, m); }
    __shared__ float red[8];
    int wv = t >> 6, l = t & 63;
    if (l == 0) { red[wv] = s; red[4 + wv] = s2; }
    __syncthreads();
    s = red[0] + red[1] + red[2] + red[3];
    s2 = red[4] + red[5] + red[6] + red[7];
    float mu = s * (1.f / 1024.f);
    float var = s2 * (1.f / 1024.f) - mu * mu;
    float inv = rsqrtf(var + 1e-5f);
    float4 wv4 = *(const float4*)(w + t * 4);
    float4 bv4 = *(const float4*)(b + t * 4);
    union { bf16 h[4]; uint2 u; } o;
    o.h[0] = (bf16)((v.x - mu) * inv * wv4.x + bv4.x);
    o.h[1] = (bf16)((v.y - mu) * inv * wv4.y + bv4.y);
    o.h[2] = (bf16)((v.z - mu) * inv * wv4.z + bv4.z);
    o.h[3] = (bf16)((v.w - mu) * inv * wv4.w + bv4.w);
    *(uint2*)(out + t * 4) = o.u;
}

// ================= 256x256 8-phase GEMM (m201 template, plain HIP) =========
// C[M][N] = A[M][K] * B[N][K]^T, bf16 in. 512 thr = 8 waves (2M x 4N),
// BK=64, LDS 128 KiB (2 dbuf x (A 256x64 + B 256x64)), one half-tile staged
// per phase, vmcnt(6) at phases 4/8 only.
// Bank swizzle: row stride = 128 B = 32 banks, so every row starts at bank 0.
// 3-bit XOR (chunk ^= row&7) spreads 8 consecutive rows across all 8 16-B
// chunks (all 32 banks); rows r/r+8 alias 2-way = free (m136). Applied as
// inverse-swizzled GLOBAL SOURCE (global_load_lds writes linearly, rule 21)
// + swizzled ds_read.
// EPI=0: bf16 C.  EPI=1: f32 out with row remap (4096-pad -> 4000) + bias.

__device__ __forceinline__ void stage_half(const bf16* __restrict__ src, int srow, int K,
                                           int kofs, bf16* ldsb, int w, int l) {
#pragma unroll
    for (int r = 0; r < 2; ++r) {
        int rh = (r * 8 + w) * 8 + (l >> 3);          // row within 128-row half
        int chunk = (l & 7) ^ (rh & 7);               // inverse 3-bit swizzle on source
        __builtin_amdgcn_global_load_lds(AS1(src + (size_t)(srow + rh) * K + kofs + chunk * 8),
                                         AS3(ldsb + (r * 8 + w) * 512), 16, 0, 0);
    }
}

__device__ __forceinline__ bf16x8 fragLD(const bf16* base, int row, int ks, int lk) {
    // swizzled read: chunk ^= row&7
    int ch = ((ks * 4 + lk) ^ (row & 7)) * 8;
    return *(const bf16x8*)(base + row * 64 + ch);
}

#define RDA(AF, base, mofs) \
    _Pragma("unroll") for (int m = 0; m < 4; ++m) \
    _Pragma("unroll") for (int ks = 0; ks < 2; ++ks) \
        AF[m][ks] = fragLD(base, rA + (mofs + m) * 16 + lrow, ks, lk);

#define RDB2(nb, base) \
    _Pragma("unroll") for (int n = 0; n < 2; ++n) \
    _Pragma("unroll") for (int ks = 0; ks < 2; ++ks) \
        bfr[(nb) + n][ks] = fragLD(base, rB + ((nb) + n) * 16 + lrow, ks, lk);

#define MM(mb, AF, nb) do { \
    __builtin_amdgcn_s_setprio(1); \
    _Pragma("unroll") for (int m = 0; m < 4; ++m) \
    _Pragma("unroll") for (int n = 0; n < 2; ++n) \
    _Pragma("unroll") for (int ks = 0; ks < 2; ++ks) \
        acc[(mb) + m][(nb) + n] = MFMA16(AF[m][ks], bfr[(nb) + n][ks], acc[(mb) + m][(nb) + n]); \
    __builtin_amdgcn_s_setprio(0); } while (0)

template <int EPI>
__global__ __launch_bounds__(512, 2) void gemm256(const bf16* __restrict__ A,
                                                  const bf16* __restrict__ B,
                                                  bf16* __restrict__ C,
                                                  float* __restrict__ Cf,
                                                  const float* __restrict__ bias,
                                                  int M, int N, int K) {
    __shared__ __align__(16) bf16 LA[2 * 16384];
    __shared__ __align__(16) bf16 LB[2 * 16384];
    const int t = threadIdx.x;
    const int w = t >> 6, l = t & 63;
    const int lrow = l & 15, lk = l >> 4;
    const int wrM = w >> 2, wn = w & 3;
    const int rA = wrM * 128, rB = wn * 64;

    // bijective XCD swizzle (grids here are divisible by 8)
    const int nwg = gridDim.x, cpx = nwg >> 3;
    const int swz = ((int)blockIdx.x & 7) * cpx + ((int)blockIdx.x >> 3);
    const int nbk = N >> 8;
    const int m0 = (swz / nbk) * 256;
    const int n0 = (swz % nbk) * 256;

    bf16* LA0 = LA;          bf16* LB0 = LB;          // even K-tiles
    bf16* LA1 = LA + 16384;  bf16* LB1 = LB + 16384;  // odd K-tiles

    f32x4 acc[8][4] = {};
    bf16x8 afL[4][2], afH[4][2], bfr[4][2];

    const int NT = K >> 6, NI = K >> 7;

    // ---- prologue: tile0 fully + tile1 {B-lo,B-hi,A-lo}; drain tile0 ----
    stage_half(B, n0,       K, 0,  LB0,        w, l);
    stage_half(B, n0 + 128, K, 0,  LB0 + 8192, w, l);
    stage_half(A, m0,       K, 0,  LA0,        w, l);
    stage_half(A, m0 + 128, K, 0,  LA0 + 8192, w, l);
    stage_half(B, n0,       K, 64, LB1,        w, l);
    stage_half(B, n0 + 128, K, 64, LB1 + 8192, w, l);
    stage_half(A, m0,       K, 64, LA1,        w, l);
    asm volatile("s_waitcnt vmcnt(6)" ::: "memory");
    BAR();

    for (int i = 0; i < NI; ++i) {
        const int kS1 = (2 * i + 1) << 6;
        const int t2 = 2 * i + 2, t3 = 2 * i + 3;
        const int kS2 = ((t2 < NT) ? t2 : NT - 1) << 6;
        const int kS3 = ((t3 < NT) ? t3 : NT - 1) << 6;

        // ---- P1: Q1 of even tile ----
        RDA(afL, LA0, 0);
        if (wn < 2) { RDB2(0, LB0); RDB2(2, LB0); } else { RDB2(0, LB0); }
        stage_half(A, m0 + 128, K, kS1, LA1 + 8192, w, l);   // odd tile A-hi
        BAR();
        MM(0, afL, 0);
        BAR();
        // ---- P2: Q2 ----
        if (wn >= 2) { RDB2(2, LB0); }
        stage_half(B, n0, K, kS2, LB0, w, l);                // t+2 B-lo
        BAR();
        MM(0, afL, 2);
        BAR();
        // ---- P3: Q3 ----
        RDA(afH, LA0, 4);
        stage_half(B, n0 + 128, K, kS2, LB0 + 8192, w, l);   // t+2 B-hi
        BAR();
        MM(4, afH, 0);
        BAR();
        // ---- P4: Q4 + counted drain ----
        stage_half(A, m0, K, kS2, LA0, w, l);                // t+2 A-lo
        BAR();
        MM(4, afH, 2);
        asm volatile("s_waitcnt vmcnt(6)" ::: "memory");
        BAR();
        // ---- P5: Q1 of odd tile ----
        RDA(afL, LA1, 0);
        if (wn < 2) { RDB2(0, LB1); RDB2(2, LB1); } else { RDB2(0, LB1); }
        stage_half(A, m0 + 128, K, kS2, LA0 + 8192, w, l);   // t+2 A-hi
        BAR();
        MM(0, afL, 0);
        BAR();
        // ---- P6: Q2 ----
        if (wn >= 2) { RDB2(2, LB1); }
        stage_half(B, n0, K, kS3, LB1, w, l);                // t+3 B-lo
        BAR();
        MM(0, afL, 2);
        BAR();
        // ---- P7: Q3 ----
        RDA(afH, LA1, 4);
        stage_half(B, n0 + 128, K, kS3, LB1 + 8192, w, l);   // t+3 B-hi
        BAR();
        MM(4, afH, 0);
        BAR();
        // ---- P8: Q4 + counted drain ----
        stage_half(A, m0, K, kS3, LA1, w, l);                // t+3 A-lo
        BAR();
        MM(4, afH, 2);
        asm volatile("s_waitcnt vmcnt(6)" ::: "memory");
        BAR();
    }

    asm volatile("s_waitcnt vmcnt(0)" ::: "memory");

    if (EPI == 0) {
#pragma unroll
        for (int m = 0; m < 8; ++m)
#pragma unroll
            for (int r = 0; r < 4; ++r) {
                size_t row = (size_t)(m0 + rA + m * 16 + lk * 4 + r);
                bf16* dst = C + row * N + n0 + rB;
#pragma unroll
                for (int n = 0; n < 4; ++n) dst[n * 16 + lrow] = (bf16)acc[m][n][r];
            }
    } else {
#pragma unroll
        for (int m = 0; m < 8; ++m)
#pragma unroll
            for (int r = 0; r < 4; ++r) {
                int row = m0 + rA + m * 16 + lk * 4 + r;
                int p = row & 4095, bb2 = row >> 12;
                if (p < 4000) {
                    float* dst = Cf + ((size_t)bb2 * 4000 + p) * 1024 + n0 + rB;
#pragma unroll
                    for (int n = 0; n < 4; ++n)
                        dst[n * 16 + lrow] = acc[m][n][r] + bias[n0 + rB + n * 16 + lrow];
                }
            }
    }
}

// ---------------- relative-position bias, skew-materialized ----------------
// blockIdx = bb*8 + g : bb=(b*16+blk)*8+h ; g picks 32 rows.
// W[i][c] = dot(Q[i], rel_emb[257+c]) ; logical SKEW[i][j] = scale*W[i][i-j+255]
// Stored PERMUTED for attn's MFMA C-layout: skewP[((bb*8+g)*4+jt)*64+l][e],
// e = mt*16+nt*4+r  ->  lane l of attn wave g reads 32 contiguous bf16.
__global__ __launch_bounds__(256, 2) void bias_skew(const bf16* __restrict__ qkv,
                                                    const bf16* __restrict__ relw,
                                                    bf16* __restrict__ skew) {
    int bidx = blockIdx.x;
    int g = bidx & 7, bb = bidx >> 3;
    int h = bb & 7, blkn = (bb >> 3) & 15, b = bb >> 7;
    int mrow0 = b * 4096 + blkn * 256 + g * 32;
    const int t = threadIdx.x, w = t >> 6, l = t & 63, lrow = l & 15, lk = l >> 4;
    __shared__ __align__(16) bf16 Qs[32 * 136];
    __shared__ __align__(16) bf16 Ws[32 * 520];

    // stage Q (32 x 128), padded stride 136
#pragma unroll
    for (int q = 0; q < 2; ++q) {
        int idx = q * 256 + t;
        int row = idx >> 4, c8 = idx & 15;
        bf16x8 v = *(const bf16x8*)(qkv + (size_t)(mrow0 + row) * 3072 + h * 128 + c8 * 8);
        *(bf16x8*)&Qs[row * 136 + c8 * 8] = v;
    }
    __syncthreads();

    // W = Q @ relw^T ; wave w owns cols [w*128, w*128+128)
    f32x4 acc[2][8] = {};
#pragma unroll
    for (int ks = 0; ks < 4; ++ks) {
        bf16x8 aq0 = *(const bf16x8*)&Qs[lrow * 136 + ks * 32 + lk * 8];
        bf16x8 aq1 = *(const bf16x8*)&Qs[(16 + lrow) * 136 + ks * 32 + lk * 8];
#pragma unroll
        for (int ct = 0; ct < 8; ++ct) {
            int c = w * 128 + ct * 16 + lrow;
            bf16x8 br = *(const bf16x8*)(relw + (size_t)c * 128 + ks * 32 + lk * 8);
            acc[0][ct] = MFMA16(aq0, br, acc[0][ct]);
            acc[1][ct] = MFMA16(aq1, br, acc[1][ct]);
        }
    }
#pragma unroll
    for (int mt = 0; mt < 2; ++mt)
#pragma unroll
        for (int ct = 0; ct < 8; ++ct)
#pragma unroll
            for (int r = 0; r < 4; ++r)
                Ws[(mt * 16 + lk * 4 + r) * 520 + w * 128 + ct * 16 + lrow] =
                    (bf16)(acc[mt][ct][r] * SCALE);
    __syncthreads();

    // permuted skew write
    int jt = t >> 6, ll = t & 63;
    bool last = (blkn == 15);
    const bf16 negbig = (bf16)NEGBIG;
    union { bf16 hh[32]; uint4 q4[4]; } ob;
#pragma unroll
    for (int e = 0; e < 32; ++e) {
        int mt = e >> 4, nt = (e >> 2) & 3, r = e & 3;
        int iloc = mt * 16 + (ll >> 4) * 4 + r;
        int j = jt * 64 + nt * 16 + (ll & 15);
        int ig = g * 32 + iloc;
        int c = ig - j + 255;
        bool masked = last && (ig >= 160 || j >= 160);
        ob.hh[e] = masked ? negbig : Ws[iloc * 520 + c];
    }
    uint4* dst = (uint4*)(skew + ((((size_t)bb * 8 + g) * 4 + jt) * 64 + ll) * 32);
#pragma unroll
    for (int qq = 0; qq < 4; ++qq) dst[qq] = ob.q4[qq];
}

// ---------------- fused block attention ----------------
// one block per (b,blk,h); 8 waves x 32 query rows; KV tiles of 64, online softmax.
__global__ __launch_bounds__(512, 2) void attn_kernel(const bf16* __restrict__ qkv,
                                                      const bf16* __restrict__ skew,
                                                      bf16* __restrict__ ao) {
    int bb = blockIdx.x;
    int h = bb & 7, blkn = (bb >> 3) & 15, b = bb >> 7;
    const int t = threadIdx.x, w = t >> 6, l = t & 63, lrow = l & 15, lk = l >> 4;
    size_t qrow0 = (size_t)(b * 4096 + blkn * 256);
    __shared__ __align__(16) bf16 Ks[64 * 136];
    __shared__ __align__(16) bf16 Vt[128 * 72];
    __shared__ __align__(16) bf16 Ps[8][32 * 72];

    int i0 = w * 32;
    bf16x8 aq[2][4];
#pragma unroll
    for (int mt = 0; mt < 2; ++mt)
#pragma unroll
        for (int ks = 0; ks < 4; ++ks)
            aq[mt][ks] = *(const bf16x8*)(qkv + (qrow0 + i0 + mt * 16 + lrow) * 3072 +
                                          h * 128 + ks * 32 + lk * 8);

    f32x4 o[2][8] = {};
    float mrun[2][4], lrun[2][4];
#pragma unroll
    for (int mt = 0; mt < 2; ++mt)
#pragma unroll
        for (int r = 0; r < 4; ++r) { mrun[mt][r] = NEGBIG; lrun[mt][r] = 0.f; }

    for (int jt = 0; jt < 4; ++jt) {
        __syncthreads();   // previous iter's LDS reads complete
        // stage K tile (rows jt*64.., padded stride 136)
#pragma unroll
        for (int q = 0; q < 2; ++q) {
            int idx = q * 512 + t;
            int row = idx >> 4, c8 = idx & 15;
            bf16x8 v = *(const bf16x8*)(qkv + (qrow0 + jt * 64 + row) * 3072 + 1024 +
                                        h * 128 + c8 * 8);
            *(bf16x8*)&Ks[row * 136 + c8 * 8] = v;
        }
        // stage V transposed: Vt[d][j]
#pragma unroll
        for (int q = 0; q < 2; ++q) {
            int idx = q * 512 + t;
            int row = idx >> 4, c8 = idx & 15;
            bf16x8 v = *(const bf16x8*)(qkv + (qrow0 + jt * 64 + row) * 3072 + 2048 +
                                        h * 128 + c8 * 8);
#pragma unroll
            for (int e = 0; e < 8; ++e) Vt[(c8 * 8 + e) * 72 + row] = v[e];
        }
        __syncthreads();

        // S = Q K^T (32 x 64 per wave)
        f32x4 s[2][4] = {};
#pragma unroll
        for (int nt = 0; nt < 4; ++nt)
#pragma unroll
            for (int ks = 0; ks < 4; ++ks) {
                bf16x8 bk = *(const bf16x8*)&Ks[(nt * 16 + lrow) * 136 + ks * 32 + lk * 8];
                s[0][nt] = MFMA16(aq[0][ks], bk, s[0][nt]);
                s[1][nt] = MFMA16(aq[1][ks], bk, s[1][nt]);
            }

        // scale + bias (permuted skew: 4 x 16B contiguous loads per lane)
        bf16x8 sk[4];
        const bf16x8* sp = (const bf16x8*)(skew +
                            ((((size_t)bb * 8 + w) * 4 + jt) * 64 + l) * 32);
        sk[0] = sp[0]; sk[1] = sp[1]; sk[2] = sp[2]; sk[3] = sp[3];
        float sv[2][4][4];
#pragma unroll
        for (int mt = 0; mt < 2; ++mt)
#pragma unroll
            for (int nt = 0; nt < 4; ++nt)
#pragma unroll
                for (int r = 0; r < 4; ++r)
                    sv[mt][nt][r] = s[mt][nt][r] * SCALE +
                                    (float)sk[mt * 2 + (nt >> 1)][(nt & 1) * 4 + r];

        // online softmax (row stats across the 16-lane col group)
#pragma unroll
        for (int mt = 0; mt < 2; ++mt)
#pragma unroll
            for (int r = 0; r < 4; ++r) {
                float mx = fmaxf(fmaxf(sv[mt][0][r], sv[mt][1][r]),
                                 fmaxf(sv[mt][2][r], sv[mt][3][r]));
#pragma unroll
                for (int d = 1; d < 16; d <<= 1) mx = fmaxf(mx, __shfl_xor(mx, d));
                float mold = mrun[mt][r];
                float mn = fmaxf(mold, mx);
                float corr = __expf(mold - mn);
                mrun[mt][r] = mn;
                float rs = 0.f;
#pragma unroll
                for (int nt = 0; nt < 4; ++nt) {
                    float e = __expf(sv[mt][nt][r] - mn);
                    sv[mt][nt][r] = e; rs += e;
                }
#pragma unroll
                for (int d = 1; d < 16; d <<= 1) rs += __shfl_xor(rs, d);
                lrun[mt][r] = lrun[mt][r] * corr + rs;
#pragma unroll
                for (int dt = 0; dt < 8; ++dt) o[mt][dt][r] *= corr;
            }

        // P -> per-wave LDS (bf16) to fix A-fragment layout
#pragma unroll
        for (int mt = 0; mt < 2; ++mt)
#pragma unroll
            for (int nt = 0; nt < 4; ++nt)
#pragma unroll
                for (int r = 0; r < 4; ++r)
                    Ps[w][(mt * 16 + lk * 4 + r) * 72 + nt * 16 + lrow] = (bf16)sv[mt][nt][r];

        // O += P @ V
#pragma unroll
        for (int pks = 0; pks < 2; ++pks) {
            bf16x8 ap0 = *(const bf16x8*)&Ps[w][lrow * 72 + pks * 32 + lk * 8];
            bf16x8 ap1 = *(const bf16x8*)&Ps[w][(16 + lrow) * 72 + pks * 32 + lk * 8];
#pragma unroll
            for (int dt = 0; dt < 8; ++dt) {
                bf16x8 bv = *(const bf16x8*)&Vt[(dt * 16 + lrow) * 72 + pks * 32 + lk * 8];
                o[0][dt] = MFMA16(ap0, bv, o[0][dt]);
                o[1][dt] = MFMA16(ap1, bv, o[1][dt]);
            }
        }
    }

    // normalize + store (layout [row][h*128+d] for the output GEMM)
#pragma unroll
    for (int mt = 0; mt < 2; ++mt)
#pragma unroll
        for (int r = 0; r < 4; ++r) {
            float inv = 1.0f / lrun[mt][r];
            size_t arow = qrow0 + i0 + mt * 16 + lk * 4 + r;
            bf16* dst = ao + arow * 1024 + h * 128;
#pragma unroll
            for (int dt = 0; dt < 8; ++dt)
                dst[dt * 16 + lrow] = (bf16)(o[mt][dt][r] * inv);
        }
}

// ---------------- host ----------------
extern "C" void kernel_launch(void* const* d_in, const int* in_sizes, int n_in,
                              void* d_out, int out_size, void* d_ws, size_t ws_size,
                              hipStream_t stream) {
    const float* x   = (const float*)d_in[0];
    const float* lnw = (const float*)d_in[1];
    const float* lnb = (const float*)d_in[2];
    const float* Wq  = (const float*)d_in[3];
    const float* Wkv = (const float*)d_in[4];
    const float* Wo  = (const float*)d_in[5];
    const float* bo  = (const float*)d_in[6];
    const float* rel = (const float*)d_in[7];

    const size_t OFF_XN   = 0;                          // 134,217,728 B (also AO)
    const size_t OFF_QKV  = OFF_XN + 134217728ULL;      // 402,653,184 B
    const size_t OFF_SKEW = OFF_QKV + 402653184ULL;     // 268,435,456 B
    const size_t OFF_WCAT = OFF_SKEW + 268435456ULL;    //   6,291,456 B
    const size_t OFF_WO   = OFF_WCAT + 6291456ULL;      //   2,097,152 B
    const size_t OFF_RELW = OFF_WO + 2097152ULL;        //     131,072 B
    const size_t NEED     = OFF_RELW + 131072ULL;       // ~776 MiB
    if (ws_size < NEED) return;   // diagnostic: will fail validation loudly

    char* ws = (char*)d_ws;
    bf16* xn   = (bf16*)(ws + OFF_XN);
    bf16* qkv  = (bf16*)(ws + OFF_QKV);
    bf16* skw  = (bf16*)(ws + OFF_SKEW);
    bf16* wcat = (bf16*)(ws + OFF_WCAT);
    bf16* wo   = (bf16*)(ws + OFF_WO);
    bf16* relw = (bf16*)(ws + OFF_RELW);
    bf16* ao   = xn;                 // reuse: xn dead after qkv GEMM
    float* out = (float*)d_out;

    cvt_bf16<<<1024, 256, 0, stream>>>(Wq, wcat, 1048576);
    cvt_bf16<<<2048, 256, 0, stream>>>(Wkv, wcat + 1048576, 2097152);
    cvt_bf16<<<1024, 256, 0, stream>>>(Wo, wo, 1048576);
    cvt_bf16<<<64, 256, 0, stream>>>(rel + 257 * 128, relw, 65536);
    ln_kernel<<<65536, 256, 0, stream>>>(x, lnw, lnb, xn);
    gemm256<0><<<3072, 512, 0, stream>>>(xn, wcat, qkv, nullptr, nullptr, 65536, 3072, 1024);
    bias_skew<<<16384, 256, 0, stream>>>(qkv, relw, skw);
    attn_kernel<<<2048, 512, 0, stream>>>(qkv, skw, ao);
    gemm256<1><<<1024, 512, 0, stream>>>(ao, wo, nullptr, out, bo, 65536, 1024, 1024);
}